// Round 2
// baseline (96436.816 us; speedup 1.0000x reference)
//
#include <hip/hip_runtime.h>

#define NWG 256
#define WGS 512

typedef __attribute__((ext_vector_type(4))) float facc4;
typedef __attribute__((ext_vector_type(8))) short bfrag8;

constexpr int B_ = 128, T_ = 512, I_ = 128, H_ = 1024;
constexpr int G_ = 4 * H_;  // 4096

// ---------------- workspace layout (bytes) ----------------
constexpr size_t OFF_BAR  = 0;
constexpr size_t OFF_H1F  = 256;
constexpr size_t OFF_H2F  = OFF_H1F + 2ull * B_ * H_ * 4;
constexpr size_t OFF_C1   = OFF_H2F + 2ull * B_ * H_ * 4;
constexpr size_t OFF_C2   = OFF_C1 + (size_t)B_ * H_ * 4;
constexpr size_t OFF_X1F  = OFF_C2 + (size_t)B_ * H_ * 4;
constexpr size_t OFF_X2F  = OFF_X1F + (size_t)B_ * I_ * 4;
constexpr size_t OFF_H1S  = OFF_X2F + (size_t)B_ * H_ * 4;
constexpr size_t OFF_H2S  = OFF_H1S + 2ull * B_ * H_ * 2;
constexpr size_t OFF_X1S  = OFF_H2S + 2ull * B_ * H_ * 2;
constexpr size_t OFF_X2S  = OFF_X1S + (size_t)B_ * I_ * 2;
constexpr size_t OFF_BS1  = OFF_X2S + (size_t)B_ * H_ * 2;
constexpr size_t OFF_BS2  = OFF_BS1 + (size_t)G_ * 4;
constexpr size_t ZERO_BYTES = OFF_BS2 + (size_t)G_ * 4;
constexpr size_t OFF_WQ1  = ZERO_BYTES;
constexpr size_t OFF_WR1  = OFF_WQ1 + 3ull * I_ * H_ * 2;
constexpr size_t OFF_WIH1 = OFF_WR1 + 2ull * H_ * I_ * 2;
constexpr size_t OFF_WHH1 = OFF_WIH1 + (size_t)G_ * I_ * 2;
constexpr size_t OFF_WQ2  = OFF_WHH1 + (size_t)G_ * H_ * 2;
constexpr size_t OFF_WR2  = OFF_WQ2 + 3ull * H_ * H_ * 2;
constexpr size_t OFF_WIH2 = OFF_WR2 + 2ull * H_ * H_ * 2;
constexpr size_t OFF_WHH2 = OFF_WIH2 + (size_t)G_ * H_ * 2;

struct GBar {
  unsigned leaf[32];
  unsigned root;
  unsigned gen;
};

__device__ __forceinline__ float sigf(float x) { return 1.0f / (1.0f + __expf(-x)); }

__device__ __forceinline__ unsigned short f2bf(float f) {
  union { float f; unsigned u; } v; v.f = f;
  unsigned r = v.u + 0x7FFFu + ((v.u >> 16) & 1u);  // RNE
  return (unsigned short)(r >> 16);
}

// ---------- device-coherent (agent-scope, sc0 sc1) data plane ----------
// Coherent loads bypass stale L1/L2 -> no acquire fences -> L2 keeps weights
// resident across barriers. Coherent stores write through to the L3 coherence
// point -> L2 has no dirty activation lines -> release writeback is ~free.
__device__ __forceinline__ float cloadf(const float* p) {
  return __hip_atomic_load(p, __ATOMIC_RELAXED, __HIP_MEMORY_SCOPE_AGENT);
}
__device__ __forceinline__ void cstoref(float* p, float v) {
  __hip_atomic_store(p, v, __ATOMIC_RELAXED, __HIP_MEMORY_SCOPE_AGENT);
}
__device__ __forceinline__ void cstoreu(unsigned* p, unsigned v) {
  __hip_atomic_store(p, v, __ATOMIC_RELAXED, __HIP_MEMORY_SCOPE_AGENT);
}
__device__ __forceinline__ bfrag8 cload_frag(const unsigned short* p) {
  union { bfrag8 f; unsigned long long u[2]; } r;
  r.u[0] = __hip_atomic_load((const unsigned long long*)p, __ATOMIC_RELAXED,
                             __HIP_MEMORY_SCOPE_AGENT);
  r.u[1] = __hip_atomic_load(((const unsigned long long*)p) + 1, __ATOMIC_RELAXED,
                             __HIP_MEMORY_SCOPE_AGENT);
  return r.f;
}
// lane-paired bf16 shadow store: even lane packs (v, neighbor v) into one u32
__device__ __forceinline__ void cstore_sh(unsigned short* base, size_t idx, float v, int lane) {
  float vo = __shfl_xor(v, 1);
  if (!(lane & 1)) {
    unsigned pk = (unsigned)f2bf(v) | ((unsigned)f2bf(vo) << 16);
    cstoreu((unsigned*)(base + idx), pk);
  }
}

// ---- fence-free device barrier (relaxed/release atomics only) ----
__device__ __forceinline__ void gbar_fast(GBar* b) {
  __syncthreads();
  if (threadIdx.x == 0) {
    unsigned g = __hip_atomic_load(&b->gen, __ATOMIC_RELAXED, __HIP_MEMORY_SCOPE_AGENT);
    int leaf = blockIdx.x >> 3;
    // RELEASE: orders this WG's coherent stores (vmcnt drain) before the add;
    // L2 is clean so the implied writeback has no work.
    unsigned a = __hip_atomic_fetch_add(&b->leaf[leaf], 1u, __ATOMIC_RELEASE,
                                        __HIP_MEMORY_SCOPE_AGENT);
    if (a == 7u) {
      unsigned r = __hip_atomic_fetch_add(&b->root, 1u, __ATOMIC_RELAXED,
                                          __HIP_MEMORY_SCOPE_AGENT);
      if (r == 31u) {
        for (int i = 0; i < 32; i++)
          __hip_atomic_store(&b->leaf[i], 0u, __ATOMIC_RELAXED, __HIP_MEMORY_SCOPE_AGENT);
        __hip_atomic_store(&b->root, 0u, __ATOMIC_RELAXED, __HIP_MEMORY_SCOPE_AGENT);
        __hip_atomic_store(&b->gen, g + 1u, __ATOMIC_RELEASE, __HIP_MEMORY_SCOPE_AGENT);
      }
    }
    while (__hip_atomic_load(&b->gen, __ATOMIC_RELAXED, __HIP_MEMORY_SCOPE_AGENT) == g)
      __builtin_amdgcn_s_sleep(1);
    asm volatile("" ::: "memory");  // no compiler reordering across the wake
  }
  __syncthreads();
}

// ---- full-fence barrier: used ONCE after init (weights written with plain stores)
__device__ __forceinline__ void gbar_init(GBar* b) {
  __syncthreads();
  if (threadIdx.x == 0) {
    __builtin_amdgcn_fence(__ATOMIC_RELEASE, "agent");
    unsigned g = __hip_atomic_load(&b->gen, __ATOMIC_RELAXED, __HIP_MEMORY_SCOPE_AGENT);
    int leaf = blockIdx.x >> 3;
    unsigned a = __hip_atomic_fetch_add(&b->leaf[leaf], 1u, __ATOMIC_RELAXED,
                                        __HIP_MEMORY_SCOPE_AGENT);
    if (a == 7u) {
      unsigned r = __hip_atomic_fetch_add(&b->root, 1u, __ATOMIC_RELAXED,
                                          __HIP_MEMORY_SCOPE_AGENT);
      if (r == 31u) {
        for (int i = 0; i < 32; i++)
          __hip_atomic_store(&b->leaf[i], 0u, __ATOMIC_RELAXED, __HIP_MEMORY_SCOPE_AGENT);
        __hip_atomic_store(&b->root, 0u, __ATOMIC_RELAXED, __HIP_MEMORY_SCOPE_AGENT);
        __hip_atomic_store(&b->gen, g + 1u, __ATOMIC_RELEASE, __HIP_MEMORY_SCOPE_AGENT);
      }
    }
    while (__hip_atomic_load(&b->gen, __ATOMIC_RELAXED, __HIP_MEMORY_SCOPE_AGENT) == g)
      __builtin_amdgcn_s_sleep(1);
    __builtin_amdgcn_fence(__ATOMIC_ACQUIRE, "agent");
  }
  __syncthreads();
}

// ---- one mogrify work unit: 2 16x16 tiles, 8 waves = 2 tiles x 4-way K-split.
__device__ __forceinline__ void mog_unit(
    const unsigned short* __restrict__ A, int K,       // bf16 activations (coherent)
    const unsigned short* __restrict__ W,              // bf16 weights (plain, L2-hot)
    const float* __restrict__ bias,
    const float* srcF, int srcStride,
    float* dstF, unsigned short* dstS,
    int N, int ntShift, int lu, float (*red)[64][4]) {
  const int tid = threadIdx.x;
  const int lane = tid & 63;
  const int wv = tid >> 6;
  const int slot = wv >> 2;
  const int role = wv & 3;
  const int tt = lu * 2 + slot;
  const int mt = tt >> ntShift;
  const int nt = tt & ((1 << ntShift) - 1);
  const int l15 = lane & 15, lq = lane >> 4;
  const unsigned short* ap = A + (size_t)(mt * 16 + l15) * K + lq * 8;
  const unsigned short* wp = W + (size_t)(nt * 16 + l15) * K + lq * 8;
  const int kq = K >> 2;
  const int kb = role * kq, ke = kb + kq;
  facc4 acc = {0.f, 0.f, 0.f, 0.f};
  for (int k = kb; k < ke; k += 32) {
    bfrag8 av = cload_frag(ap + k);
    bfrag8 bv = *(const bfrag8*)(wp + k);
    acc = __builtin_amdgcn_mfma_f32_16x16x32_bf16(av, bv, acc, 0, 0, 0);
  }
  red[wv][lane][0] = acc[0]; red[wv][lane][1] = acc[1];
  red[wv][lane][2] = acc[2]; red[wv][lane][3] = acc[3];
  __syncthreads();
  if (role == 0) {
    const int n = nt * 16 + l15;
    const float bn = bias[n];
#pragma unroll
    for (int j = 0; j < 4; j++) {
      float d = red[slot * 4 + 0][lane][j] + red[slot * 4 + 1][lane][j] +
                red[slot * 4 + 2][lane][j] + red[slot * 4 + 3][lane][j];
      const int m = mt * 16 + lq * 4 + j;
      float v = 2.0f * sigf(d + bn) * cloadf(&srcF[(size_t)m * srcStride + n]);
      cstoref(&dstF[(size_t)m * N + n], v);
      cstore_sh(dstS, (size_t)m * N + n, v, lane);
    }
  }
  __syncthreads();
}

// ---- one LSTM-cell work unit: 2 16x16 tiles over H, 8 waves = 2 tiles x 4 gates.
__device__ __forceinline__ void cell_unit(
    const unsigned short* __restrict__ X, int Kx,
    const unsigned short* __restrict__ Hm,
    const unsigned short* __restrict__ Wih,
    const unsigned short* __restrict__ Whh,
    const float* __restrict__ bsum,
    float* c, float* hF, unsigned short* hS,
    int lu, float (*red)[64][4]) {
  const int tid = threadIdx.x;
  const int lane = tid & 63;
  const int wv = tid >> 6;
  const int slot = wv >> 2;
  const int gate = wv & 3;
  const int tt = lu * 2 + slot;
  const int mt = tt >> 6;
  const int nt = tt & 63;
  const int l15 = lane & 15, lq = lane >> 4;
  const int wrow = gate * H_ + nt * 16 + l15;
  const unsigned short* xp = X + (size_t)(mt * 16 + l15) * Kx + lq * 8;
  const unsigned short* wi = Wih + (size_t)wrow * Kx + lq * 8;
  const unsigned short* hp = Hm + (size_t)(mt * 16 + l15) * H_ + lq * 8;
  const unsigned short* wh = Whh + (size_t)wrow * H_ + lq * 8;
  facc4 acc = {0.f, 0.f, 0.f, 0.f};
  for (int k = 0; k < Kx; k += 32)
    acc = __builtin_amdgcn_mfma_f32_16x16x32_bf16(cload_frag(xp + k),
                                                  *(const bfrag8*)(wi + k), acc, 0, 0, 0);
  for (int k = 0; k < H_; k += 32)
    acc = __builtin_amdgcn_mfma_f32_16x16x32_bf16(cload_frag(hp + k),
                                                  *(const bfrag8*)(wh + k), acc, 0, 0, 0);
  red[wv][lane][0] = acc[0]; red[wv][lane][1] = acc[1];
  red[wv][lane][2] = acc[2]; red[wv][lane][3] = acc[3];
  __syncthreads();
  if (gate == 0) {
    const int n = nt * 16 + l15;
    const float bi = bsum[n], bf = bsum[H_ + n], bg = bsum[2 * H_ + n], bo = bsum[3 * H_ + n];
#pragma unroll
    for (int j = 0; j < 4; j++) {
      float iv = sigf(red[slot * 4 + 0][lane][j] + bi);
      float fv = sigf(red[slot * 4 + 1][lane][j] + bf);
      float gv = tanhf(red[slot * 4 + 2][lane][j] + bg);
      float ov = sigf(red[slot * 4 + 3][lane][j] + bo);
      const int m = mt * 16 + lq * 4 + j;
      const size_t idx = (size_t)m * H_ + n;
      float cold = cloadf(&c[idx]);
      float cn = fv * cold + iv * gv;
      float hn = ov * tanhf(cn);
      cstoref(&c[idx], cn);
      cstoref(&hF[idx], hn);
      cstore_sh(hS, idx, hn, lane);
    }
  }
  __syncthreads();
}

__global__ __launch_bounds__(WGS, 2) void moglstm_kernel(
    const float* __restrict__ in_seq,
    const float* __restrict__ c1Q, const float* __restrict__ c1Qb,
    const float* __restrict__ c1R, const float* __restrict__ c1Rb,
    const float* __restrict__ c1Wih, const float* __restrict__ c1Whh,
    const float* __restrict__ c1bih, const float* __restrict__ c1bhh,
    const float* __restrict__ c2Q, const float* __restrict__ c2Qb,
    const float* __restrict__ c2R, const float* __restrict__ c2Rb,
    const float* __restrict__ c2Wih, const float* __restrict__ c2Whh,
    const float* __restrict__ c2bih, const float* __restrict__ c2bhh,
    const float* __restrict__ linW, const float* __restrict__ linb,
    char* ws, float* __restrict__ out) {
  __shared__ float red[8][64][4];

  GBar* bar = (GBar*)(ws + OFF_BAR);
  float* h1f0 = (float*)(ws + OFF_H1F);
  float* h1f1 = h1f0 + (size_t)B_ * H_;
  float* h2f0 = (float*)(ws + OFF_H2F);
  float* h2f1 = h2f0 + (size_t)B_ * H_;
  float* c1f = (float*)(ws + OFF_C1);
  float* c2f = (float*)(ws + OFF_C2);
  float* x1f = (float*)(ws + OFF_X1F);
  float* x2f = (float*)(ws + OFF_X2F);
  unsigned short* h1s0 = (unsigned short*)(ws + OFF_H1S);
  unsigned short* h1s1 = h1s0 + (size_t)B_ * H_;
  unsigned short* h2s0 = (unsigned short*)(ws + OFF_H2S);
  unsigned short* h2s1 = h2s0 + (size_t)B_ * H_;
  unsigned short* x1s = (unsigned short*)(ws + OFF_X1S);
  unsigned short* x2s = (unsigned short*)(ws + OFF_X2S);
  float* bs1 = (float*)(ws + OFF_BS1);
  float* bs2 = (float*)(ws + OFF_BS2);
  unsigned short* wq1 = (unsigned short*)(ws + OFF_WQ1);
  unsigned short* wr1 = (unsigned short*)(ws + OFF_WR1);
  unsigned short* wih1 = (unsigned short*)(ws + OFF_WIH1);
  unsigned short* whh1 = (unsigned short*)(ws + OFF_WHH1);
  unsigned short* wq2 = (unsigned short*)(ws + OFF_WQ2);
  unsigned short* wr2 = (unsigned short*)(ws + OFF_WR2);
  unsigned short* wih2 = (unsigned short*)(ws + OFF_WIH2);
  unsigned short* whh2 = (unsigned short*)(ws + OFF_WHH2);

  // ---- init: fp32 -> bf16 weight conversion + bias sums (plain stores)
  {
    size_t gt = (size_t)blockIdx.x * WGS + threadIdx.x;
    const size_t gs = (size_t)NWG * WGS;
    const float* srcs[8] = {c1Q, c1R, c1Wih, c1Whh, c2Q, c2R, c2Wih, c2Whh};
    unsigned short* dsts[8] = {wq1, wr1, wih1, whh1, wq2, wr2, wih2, whh2};
    const size_t cnts[8] = {3ull * I_ * H_, 2ull * H_ * I_, (size_t)G_ * I_,
                            (size_t)G_ * H_, 3ull * H_ * H_, 2ull * H_ * H_,
                            (size_t)G_ * H_, (size_t)G_ * H_};
    for (int a = 0; a < 8; a++)
      for (size_t i = gt; i < cnts[a]; i += gs) dsts[a][i] = f2bf(srcs[a][i]);
    for (size_t i = gt; i < (size_t)G_; i += gs) bs1[i] = c1bih[i] + c1bhh[i];
    for (size_t i = gt; i < (size_t)G_; i += gs) bs2[i] = c2bih[i] + c2bhh[i];
  }
  gbar_init(bar);  // full fences ONCE: publish plain-stored weights everywhere

  const int wg = blockIdx.x;
  for (int p = 0; p <= T_; ++p) {
    const int q = p & 1;
    const int q2 = 1 - q;
    const bool doL1 = (p < T_);
    const bool doL2 = (p > 0);
    float* h1q = q ? h1f1 : h1f0;
    float* h1o = q ? h1f0 : h1f1;
    unsigned short* h1sq = q ? h1s1 : h1s0;
    unsigned short* h1so = q ? h1s0 : h1s1;
    float* h2q2 = q2 ? h2f1 : h2f0;
    float* h2o = q ? h2f1 : h2f0;
    unsigned short* h2sq2 = q2 ? h2s1 : h2s0;
    unsigned short* h2so = q ? h2s1 : h2s0;

    for (int s = 0; s < 6; ++s) {
      const int u2 = doL2 ? 256 : 0;
      const int u1 = doL1 ? ((s == 1 || s == 3 || s == 5) ? 256 : 32) : 0;
      for (int u = wg; u < u2 + u1; u += NWG) {
        if (u < u2) {
          const int lu = u;
          switch (s) {
            case 0: mog_unit(h2sq2, H_, wq2, c2Qb, h1q, H_, x2f, x2s, H_, 6, lu, red); break;
            case 1: mog_unit(x2s, H_, wr2, c2Rb, h2q2, H_, h2q2, h2sq2, H_, 6, lu, red); break;
            case 2: mog_unit(h2sq2, H_, wq2 + 1ull * H_ * H_, c2Qb + H_, x2f, H_, x2f, x2s, H_, 6, lu, red); break;
            case 3: mog_unit(x2s, H_, wr2 + 1ull * H_ * H_, c2Rb + H_, h2q2, H_, h2q2, h2sq2, H_, 6, lu, red); break;
            case 4: mog_unit(h2sq2, H_, wq2 + 2ull * H_ * H_, c2Qb + 2 * H_, x2f, H_, x2f, x2s, H_, 6, lu, red); break;
            case 5: cell_unit(x2s, H_, h2sq2, wih2, whh2, bs2, c2f, h2o, h2so, lu, red); break;
          }
        } else {
          const int lu = u - u2;
          switch (s) {
            case 0: mog_unit(h1sq, H_, wq1, c1Qb, in_seq + (size_t)p * I_, T_ * I_, x1f, x1s, I_, 3, lu, red); break;
            case 1: mog_unit(x1s, I_, wr1, c1Rb, h1q, H_, h1q, h1sq, H_, 6, lu, red); break;
            case 2: mog_unit(h1sq, H_, wq1 + 1ull * I_ * H_, c1Qb + I_, x1f, I_, x1f, x1s, I_, 3, lu, red); break;
            case 3: mog_unit(x1s, I_, wr1 + 1ull * H_ * I_, c1Rb + H_, h1q, H_, h1q, h1sq, H_, 6, lu, red); break;
            case 4: mog_unit(h1sq, H_, wq1 + 2ull * I_ * H_, c1Qb + 2 * I_, x1f, I_, x1f, x1s, I_, 3, lu, red); break;
            case 5: cell_unit(x1s, I_, h1sq, wih1, whh1, bs1, c1f, h1o, h1so, lu, red); break;
          }
        }
      }
      gbar_fast(bar);
    }
  }

  // ---- final linear: out[b] = dot(h2_final[b,:], linW) + linb (parity 0)
  if (wg == 0) {
    float* rf = (float*)red;
    const int tid = threadIdx.x;
    const int b = tid >> 2, qq = tid & 3;
    const float* row = h2f0 + (size_t)b * H_ + qq * 256;
    const float* w = linW + qq * 256;
    float s = 0.f;
    for (int k = 0; k < 256; k++) s += cloadf(&row[k]) * w[k];
    rf[tid] = s;
    __syncthreads();
    if (tid < B_)
      out[tid] = rf[tid * 4] + rf[tid * 4 + 1] + rf[tid * 4 + 2] + rf[tid * 4 + 3] + linb[0];
  }
}

extern "C" void kernel_launch(void* const* d_in, const int* in_sizes, int n_in,
                              void* d_out, int out_size, void* d_ws, size_t ws_size,
                              hipStream_t stream) {
  const float* in_seq = (const float*)d_in[0];
  const float* c1Q = (const float*)d_in[1];
  const float* c1Qb = (const float*)d_in[2];
  const float* c1R = (const float*)d_in[3];
  const float* c1Rb = (const float*)d_in[4];
  const float* c1Wih = (const float*)d_in[5];
  const float* c1Whh = (const float*)d_in[6];
  const float* c1bih = (const float*)d_in[7];
  const float* c1bhh = (const float*)d_in[8];
  const float* c2Q = (const float*)d_in[9];
  const float* c2Qb = (const float*)d_in[10];
  const float* c2R = (const float*)d_in[11];
  const float* c2Rb = (const float*)d_in[12];
  const float* c2Wih = (const float*)d_in[13];
  const float* c2Whh = (const float*)d_in[14];
  const float* c2bih = (const float*)d_in[15];
  const float* c2bhh = (const float*)d_in[16];
  const float* linW = (const float*)d_in[17];
  const float* linb = (const float*)d_in[18];

  hipMemsetAsync(d_ws, 0, ZERO_BYTES, stream);
  moglstm_kernel<<<dim3(NWG), dim3(WGS), 0, stream>>>(
      in_seq, c1Q, c1Qb, c1R, c1Rb, c1Wih, c1Whh, c1bih, c1bhh,
      c2Q, c2Qb, c2R, c2Rb, c2Wih, c2Whh, c2bih, c2bhh,
      linW, linb, (char*)d_ws, (float*)d_out);
}

// Round 3
// 67463.544 us; speedup vs baseline: 1.4295x; 1.4295x over previous
//
#include <hip/hip_runtime.h>

#define NWG 256
#define WGS 512

typedef __attribute__((ext_vector_type(4))) float facc4;
typedef __attribute__((ext_vector_type(8))) short bfrag8;

#define MFMA_BF16 __builtin_amdgcn_mfma_f32_16x16x32_bf16

constexpr int B_ = 128, T_ = 512, I_ = 128, H_ = 1024;
constexpr int G_ = 4 * H_;  // 4096

// ---------------- workspace layout (bytes) ----------------
constexpr size_t OFF_BAR  = 0;
constexpr size_t OFF_H1F  = 256;
constexpr size_t OFF_H2F  = OFF_H1F + 2ull * B_ * H_ * 4;
constexpr size_t OFF_C1   = OFF_H2F + 2ull * B_ * H_ * 4;
constexpr size_t OFF_C2   = OFF_C1 + (size_t)B_ * H_ * 4;
constexpr size_t OFF_X1F  = OFF_C2 + (size_t)B_ * H_ * 4;
constexpr size_t OFF_X2F  = OFF_X1F + (size_t)B_ * I_ * 4;
constexpr size_t OFF_H1S  = OFF_X2F + (size_t)B_ * H_ * 4;
constexpr size_t OFF_H2S  = OFF_H1S + 2ull * B_ * H_ * 2;
constexpr size_t OFF_X1S  = OFF_H2S + 2ull * B_ * H_ * 2;
constexpr size_t OFF_X2S  = OFF_X1S + (size_t)B_ * I_ * 2;
constexpr size_t OFF_BS1  = OFF_X2S + (size_t)B_ * H_ * 2;
constexpr size_t OFF_BS2  = OFF_BS1 + (size_t)G_ * 4;
constexpr size_t ZERO_BYTES = OFF_BS2 + (size_t)G_ * 4;
// bf16 weights kept in L2 (converted in-kernel each launch)
constexpr size_t OFF_WQ1  = ZERO_BYTES;                         // 3*I*H
constexpr size_t OFF_WR1  = OFF_WQ1 + 3ull * I_ * H_ * 2;       // 2*H*I
constexpr size_t OFF_WIH1 = OFF_WR1 + 2ull * H_ * I_ * 2;       // G*I
constexpr size_t OFF_WHH1 = OFF_WIH1 + (size_t)G_ * I_ * 2;     // G*H
constexpr size_t OFF_WQ2  = OFF_WHH1 + (size_t)G_ * H_ * 2;     // 3*H*H
constexpr size_t OFF_WR2  = OFF_WQ2 + 3ull * H_ * H_ * 2;       // 2*H*H
// cell-L2 weights live in LDS now; this region is reused for fp32 partials:
constexpr size_t OFF_PART = OFF_WR2 + 2ull * H_ * H_ * 2;       // 4*128*4096 fp32 = 8 MB

// ---------------- dynamic LDS layout (bytes) ----------------
// [0, PIN_BYTES): cell-L2 pinned weight K-slice, 64 rows (gate*16+r) x stride 520 els
// [PIN_BYTES, +ASTAGE): A-staging buffer (max: 64 rows x 520 els for cell-L2)
constexpr int PIN_STRIDE = 520;   // 512 + 8 pad (elements)
constexpr size_t PIN_BYTES = 64ull * PIN_STRIDE * 2;            // 66560
constexpr size_t ASTAGE_BYTES = 64ull * PIN_STRIDE * 2;         // 66560 (>= 16x1032, 16x1160)
constexpr size_t DYN_LDS = PIN_BYTES + ASTAGE_BYTES;            // 133120

struct GBar {
  unsigned leaf[32];
  unsigned root;
  unsigned gen;
};

__device__ __forceinline__ float sigf(float x) { return 1.0f / (1.0f + __expf(-x)); }

__device__ __forceinline__ unsigned short f2bf(float f) {
  union { float f; unsigned u; } v; v.f = f;
  unsigned r = v.u + 0x7FFFu + ((v.u >> 16) & 1u);  // RNE
  return (unsigned short)(r >> 16);
}

// ---------- device-coherent (sc0 sc1) data plane for cross-WG data ----------
__device__ __forceinline__ float cloadf(const float* p) {
  return __hip_atomic_load(p, __ATOMIC_RELAXED, __HIP_MEMORY_SCOPE_AGENT);
}
__device__ __forceinline__ void cstoref(float* p, float v) {
  __hip_atomic_store(p, v, __ATOMIC_RELAXED, __HIP_MEMORY_SCOPE_AGENT);
}
__device__ __forceinline__ void cstoreu(unsigned* p, unsigned v) {
  __hip_atomic_store(p, v, __ATOMIC_RELAXED, __HIP_MEMORY_SCOPE_AGENT);
}
// pack bf16 shadow pairs: even lane stores (v, neighbor v) as one u32
__device__ __forceinline__ void cstore_sh(unsigned short* base, size_t idx, float v, int lane) {
  float vo = __shfl_xor(v, 1);
  if (!(lane & 1)) {
    unsigned pk = (unsigned)f2bf(v) | ((unsigned)f2bf(vo) << 16);
    cstoreu((unsigned*)(base + idx), pk);
  }
}

// bulk coherent stage: rows x (C4*4) bf16 elements -> LDS (called by whole WG)
template <int C4>
__device__ __forceinline__ void stage_coh(unsigned short* lds, int ldsStride, int ldsColOff,
                                          const unsigned short* src, int srcStride, int rows) {
  const int total = rows * C4;
  for (int i = threadIdx.x; i < total; i += WGS) {
    int r = i / C4, q = (i % C4) * 4;
    unsigned long long v = __hip_atomic_load(
        (const unsigned long long*)(src + (size_t)r * srcStride + q),
        __ATOMIC_RELAXED, __HIP_MEMORY_SCOPE_AGENT);
    *(unsigned long long*)(lds + (size_t)r * ldsStride + ldsColOff + q) = v;
  }
}

// ---- fence-free device barrier. Safe because __syncthreads drains every
// wave's vmcnt (coherent stores are then at L3), and all cross-WG data is sc0/sc1.
__device__ __forceinline__ void gbar_fast(GBar* b) {
  __syncthreads();
  if (threadIdx.x == 0) {
    unsigned g = __hip_atomic_load(&b->gen, __ATOMIC_RELAXED, __HIP_MEMORY_SCOPE_AGENT);
    int leaf = blockIdx.x >> 3;
    unsigned a = __hip_atomic_fetch_add(&b->leaf[leaf], 1u, __ATOMIC_RELAXED,
                                        __HIP_MEMORY_SCOPE_AGENT);
    if (a == 7u) {
      unsigned r = __hip_atomic_fetch_add(&b->root, 1u, __ATOMIC_RELAXED,
                                          __HIP_MEMORY_SCOPE_AGENT);
      if (r == 31u) {
        for (int i = 0; i < 32; i++)
          __hip_atomic_store(&b->leaf[i], 0u, __ATOMIC_RELAXED, __HIP_MEMORY_SCOPE_AGENT);
        __hip_atomic_store(&b->root, 0u, __ATOMIC_RELAXED, __HIP_MEMORY_SCOPE_AGENT);
        // release: leaf resets must be visible before the new generation
        __hip_atomic_store(&b->gen, g + 1u, __ATOMIC_RELEASE, __HIP_MEMORY_SCOPE_AGENT);
      }
    }
    while (__hip_atomic_load(&b->gen, __ATOMIC_RELAXED, __HIP_MEMORY_SCOPE_AGENT) == g)
      __builtin_amdgcn_s_sleep(1);
    asm volatile("" ::: "memory");
  }
  __syncthreads();
}

// ---- full-fence barrier: ONCE after init (weights are plain stores)
__device__ __forceinline__ void gbar_init(GBar* b) {
  __syncthreads();
  if (threadIdx.x == 0) {
    __builtin_amdgcn_fence(__ATOMIC_RELEASE, "agent");
    unsigned g = __hip_atomic_load(&b->gen, __ATOMIC_RELAXED, __HIP_MEMORY_SCOPE_AGENT);
    int leaf = blockIdx.x >> 3;
    unsigned a = __hip_atomic_fetch_add(&b->leaf[leaf], 1u, __ATOMIC_RELAXED,
                                        __HIP_MEMORY_SCOPE_AGENT);
    if (a == 7u) {
      unsigned r = __hip_atomic_fetch_add(&b->root, 1u, __ATOMIC_RELAXED,
                                          __HIP_MEMORY_SCOPE_AGENT);
      if (r == 31u) {
        for (int i = 0; i < 32; i++)
          __hip_atomic_store(&b->leaf[i], 0u, __ATOMIC_RELAXED, __HIP_MEMORY_SCOPE_AGENT);
        __hip_atomic_store(&b->root, 0u, __ATOMIC_RELAXED, __HIP_MEMORY_SCOPE_AGENT);
        __hip_atomic_store(&b->gen, g + 1u, __ATOMIC_RELEASE, __HIP_MEMORY_SCOPE_AGENT);
      }
    }
    while (__hip_atomic_load(&b->gen, __ATOMIC_RELAXED, __HIP_MEMORY_SCOPE_AGENT) == g)
      __builtin_amdgcn_s_sleep(1);
    __builtin_amdgcn_fence(__ATOMIC_ACQUIRE, "agent");
  }
  __syncthreads();
}

// ---- mogrify unit: 2 16x16 tiles (same mt), 8 waves = 2 nt-slots x 4 K-roles.
// A staged into LDS (coherent); W from global (L2-resident).
template <int K>
__device__ __forceinline__ void mog_unit(
    const unsigned short* __restrict__ A,
    const unsigned short* __restrict__ W,
    const float* __restrict__ bias,
    const float* srcF, int srcStride,
    float* dstF, unsigned short* dstS,
    int N, int ntShift, int lu, unsigned short* As, float (*red)[4][64]) {
  const int tid = threadIdx.x;
  const int lane = tid & 63;
  const int wv = tid >> 6;
  const int slot = wv >> 2;
  const int role = wv & 3;
  const int tt0 = lu * 2;
  const int mt = tt0 >> ntShift;                     // same for both slots
  const int nt = (tt0 + slot) & ((1 << ntShift) - 1);
  const int l15 = lane & 15, lq = lane >> 4;
  constexpr int LSTR = K + 8;

  stage_coh<K / 4>(As, LSTR, 0, A + (size_t)(mt * 16) * K, K, 16);
  __syncthreads();

  const unsigned short* ap = As + l15 * LSTR + lq * 8;
  const unsigned short* wp = W + (size_t)(nt * 16 + l15) * K + lq * 8;
  constexpr int kq = K / 4;
  facc4 acc = {0.f, 0.f, 0.f, 0.f};
#pragma unroll
  for (int k = 0; k < kq; k += 32)
    acc = MFMA_BF16(*(const bfrag8*)(ap + role * kq + k),
                    *(const bfrag8*)(wp + role * kq + k), acc, 0, 0, 0);
  red[wv][0][lane] = acc[0]; red[wv][1][lane] = acc[1];
  red[wv][2][lane] = acc[2]; red[wv][3][lane] = acc[3];
  __syncthreads();
  if (role == 0) {
    const int n = nt * 16 + l15;
    const float bn = bias[n];
#pragma unroll
    for (int j = 0; j < 4; j++) {
      float d = red[slot * 4 + 0][j][lane] + red[slot * 4 + 1][j][lane] +
                red[slot * 4 + 2][j][lane] + red[slot * 4 + 3][j][lane];
      const int m = mt * 16 + lq * 4 + j;
      float v = 2.0f * sigf(d + bn) * cloadf(&srcF[(size_t)m * srcStride + n]);
      cstoref(&dstF[(size_t)m * N + n], v);
      cstore_sh(dstS, (size_t)m * N + n, v, lane);
    }
  }
  __syncthreads();
}

// ---- layer-1 LSTM cell unit (tile partition): 2 tiles (same mt), waves = slot x gate.
// Weights from global (L2-resident). A ([x|h], 1152 cols) staged into LDS.
__device__ __forceinline__ void cell1_unit(
    const unsigned short* __restrict__ X,   // 128x128 bf16
    const unsigned short* __restrict__ Hm,  // 128x1024 bf16
    const unsigned short* __restrict__ Wih, // 4096x128
    const unsigned short* __restrict__ Whh, // 4096x1024
    const float* __restrict__ bsum,
    float* c, float* hF, unsigned short* hS,
    int lu, unsigned short* As, float (*red)[4][64]) {
  const int tid = threadIdx.x;
  const int lane = tid & 63;
  const int wv = tid >> 6;
  const int slot = wv >> 2;
  const int gate = wv & 3;
  const int tt0 = lu * 2;
  const int mt = tt0 >> 6;
  const int nt = (tt0 + slot) & 63;
  const int l15 = lane & 15, lq = lane >> 4;
  constexpr int LSTR = 1160;  // 128 + 1024 + 8 pad

  stage_coh<32>(As, LSTR, 0, X + (size_t)(mt * 16) * 128, 128, 16);
  stage_coh<256>(As, LSTR, 128, Hm + (size_t)(mt * 16) * 1024, 1024, 16);
  __syncthreads();

  const unsigned short* apx = As + l15 * LSTR + lq * 8;
  const int wrow = gate * H_ + nt * 16 + l15;
  const unsigned short* wi = Wih + (size_t)wrow * 128 + lq * 8;
  const unsigned short* wh = Whh + (size_t)wrow * 1024 + lq * 8;
  facc4 acc = {0.f, 0.f, 0.f, 0.f};
#pragma unroll
  for (int k = 0; k < 128; k += 32)
    acc = MFMA_BF16(*(const bfrag8*)(apx + k), *(const bfrag8*)(wi + k), acc, 0, 0, 0);
#pragma unroll 4
  for (int k = 0; k < 1024; k += 32)
    acc = MFMA_BF16(*(const bfrag8*)(apx + 128 + k), *(const bfrag8*)(wh + k), acc, 0, 0, 0);
  red[wv][0][lane] = acc[0]; red[wv][1][lane] = acc[1];
  red[wv][2][lane] = acc[2]; red[wv][3][lane] = acc[3];
  __syncthreads();
  if (gate == 0) {
    const int n = nt * 16 + l15;
    const float bi = bsum[n], bf = bsum[H_ + n], bg = bsum[2 * H_ + n], bo = bsum[3 * H_ + n];
#pragma unroll
    for (int j = 0; j < 4; j++) {
      float iv = sigf(red[slot * 4 + 0][j][lane] + bi);
      float fv = sigf(red[slot * 4 + 1][j][lane] + bf);
      float gv = tanhf(red[slot * 4 + 2][j][lane] + bg);
      float ov = sigf(red[slot * 4 + 3][j][lane] + bo);
      const int m = mt * 16 + lq * 4 + j;
      const size_t idx = (size_t)m * H_ + n;
      float cold = cloadf(&c[idx]);
      float cn = fv * cold + iv * gv;
      float hn = ov * tanhf(cn);
      cstoref(&c[idx], cn);
      cstoref(&hF[idx], hn);
      cstore_sh(hS, idx, hn, lane);
    }
  }
  __syncthreads();
}

// ---- layer-2 cell partial GEMM: WG w owns nt=w&63 (16 gate-interleaved cols per gate)
// and K-quarter role=w>>6. Weights PINNED in LDS. Writes fp32 partials.
__device__ __forceinline__ void cell2_partial(
    const unsigned short* __restrict__ X,   // x2s 128x1024
    const unsigned short* __restrict__ Hm,  // h2s 128x1024
    const unsigned short* pinW, float* part, int w, unsigned short* As) {
  const int nt = w & 63, role = w >> 6;
  const int tid = threadIdx.x;
  const int lane = tid & 63;
  const int wv = tid >> 6;
  const int gate = wv >> 1;
  const int jj = wv & 1;
  const int l15 = lane & 15, lq = lane >> 4;
  const unsigned short* src = (role < 2) ? X : Hm;
  const int colOff = (role & 1) * 512;
  const unsigned short* wp = pinW + (gate * 16 + l15) * PIN_STRIDE + lq * 8;

  for (int sb = 0; sb < 2; sb++) {
    stage_coh<128>(As, PIN_STRIDE, 0, src + ((size_t)sb * 64) * 1024 + colOff, 1024, 64);
    __syncthreads();
#pragma unroll
    for (int t = 0; t < 2; t++) {
      const int mloc = jj * 2 + t;  // 0..3 within this sb
      const unsigned short* ap = As + (mloc * 16 + l15) * PIN_STRIDE + lq * 8;
      facc4 acc = {0.f, 0.f, 0.f, 0.f};
#pragma unroll
      for (int k = 0; k < 512; k += 32)
        acc = MFMA_BF16(*(const bfrag8*)(ap + k), *(const bfrag8*)(wp + k), acc, 0, 0, 0);
#pragma unroll
      for (int j = 0; j < 4; j++) {
        const int m = sb * 64 + mloc * 16 + lq * 4 + j;
        cstoref(part + ((size_t)role * 128 + m) * G_ + gate * H_ + nt * 16 + l15, acc[j]);
      }
    }
    __syncthreads();
  }
}

// ---- layer-2 cell reduce + LSTM epilogue: WG w -> row m=w&127, col-half=w>>7.
__device__ __forceinline__ void cell2_reduce(
    const float* part, const float* __restrict__ bsum,
    float* c, float* hF, unsigned short* hS, int w) {
  const int m = w & 127, half = w >> 7;
  const int tid = threadIdx.x;
  const int n = half * 512 + tid;
  float g4[4];
#pragma unroll
  for (int g = 0; g < 4; g++) {
    float s = 0.f;
#pragma unroll
    for (int r = 0; r < 4; r++)
      s += cloadf(part + ((size_t)r * 128 + m) * G_ + g * H_ + n);
    g4[g] = s;
  }
  float iv = sigf(g4[0] + bsum[n]);
  float fv = sigf(g4[1] + bsum[H_ + n]);
  float gv = tanhf(g4[2] + bsum[2 * H_ + n]);
  float ov = sigf(g4[3] + bsum[3 * H_ + n]);
  const size_t idx = (size_t)m * H_ + n;
  float cold = cloadf(&c[idx]);
  float cn = fv * cold + iv * gv;
  float hn = ov * tanhf(cn);
  cstoref(&c[idx], cn);
  cstoref(&hF[idx], hn);
  cstore_sh(hS, idx, hn, tid & 63);
}

__global__ __launch_bounds__(WGS, 1) void moglstm_kernel(
    const float* __restrict__ in_seq,
    const float* __restrict__ c1Q, const float* __restrict__ c1Qb,
    const float* __restrict__ c1R, const float* __restrict__ c1Rb,
    const float* __restrict__ c1Wih, const float* __restrict__ c1Whh,
    const float* __restrict__ c1bih, const float* __restrict__ c1bhh,
    const float* __restrict__ c2Q, const float* __restrict__ c2Qb,
    const float* __restrict__ c2R, const float* __restrict__ c2Rb,
    const float* __restrict__ c2Wih, const float* __restrict__ c2Whh,
    const float* __restrict__ c2bih, const float* __restrict__ c2bhh,
    const float* __restrict__ linW, const float* __restrict__ linb,
    char* ws, float* __restrict__ out) {
  __shared__ float red[8][4][64];
  extern __shared__ char dynlds[];
  unsigned short* pinW = (unsigned short*)dynlds;
  unsigned short* As = (unsigned short*)(dynlds + PIN_BYTES);

  GBar* bar = (GBar*)(ws + OFF_BAR);
  float* h1f0 = (float*)(ws + OFF_H1F);
  float* h1f1 = h1f0 + (size_t)B_ * H_;
  float* h2f0 = (float*)(ws + OFF_H2F);
  float* h2f1 = h2f0 + (size_t)B_ * H_;
  float* c1f = (float*)(ws + OFF_C1);
  float* c2f = (float*)(ws + OFF_C2);
  float* x1f = (float*)(ws + OFF_X1F);
  float* x2f = (float*)(ws + OFF_X2F);
  unsigned short* h1s0 = (unsigned short*)(ws + OFF_H1S);
  unsigned short* h1s1 = h1s0 + (size_t)B_ * H_;
  unsigned short* h2s0 = (unsigned short*)(ws + OFF_H2S);
  unsigned short* h2s1 = h2s0 + (size_t)B_ * H_;
  unsigned short* x1s = (unsigned short*)(ws + OFF_X1S);
  unsigned short* x2s = (unsigned short*)(ws + OFF_X2S);
  float* bs1 = (float*)(ws + OFF_BS1);
  float* bs2 = (float*)(ws + OFF_BS2);
  unsigned short* wq1 = (unsigned short*)(ws + OFF_WQ1);
  unsigned short* wr1 = (unsigned short*)(ws + OFF_WR1);
  unsigned short* wih1 = (unsigned short*)(ws + OFF_WIH1);
  unsigned short* whh1 = (unsigned short*)(ws + OFF_WHH1);
  unsigned short* wq2 = (unsigned short*)(ws + OFF_WQ2);
  unsigned short* wr2 = (unsigned short*)(ws + OFF_WR2);
  float* part = (float*)(ws + OFF_PART);

  const int wg = blockIdx.x;

  // ---- init: fp32 -> bf16 weight conversion (plain stores) + bias sums
  {
    size_t gt = (size_t)wg * WGS + threadIdx.x;
    const size_t gs = (size_t)NWG * WGS;
    const float* srcs[6] = {c1Q, c1R, c1Wih, c1Whh, c2Q, c2R};
    unsigned short* dsts[6] = {wq1, wr1, wih1, whh1, wq2, wr2};
    const size_t cnts[6] = {3ull * I_ * H_, 2ull * H_ * I_, (size_t)G_ * I_,
                            (size_t)G_ * H_, 3ull * H_ * H_, 2ull * H_ * H_};
    for (int a = 0; a < 6; a++)
      for (size_t i = gt; i < cnts[a]; i += gs) dsts[a][i] = f2bf(srcs[a][i]);
    for (size_t i = gt; i < (size_t)G_; i += gs) bs1[i] = c1bih[i] + c1bhh[i];
    for (size_t i = gt; i < (size_t)G_; i += gs) bs2[i] = c2bih[i] + c2bhh[i];
  }
  // ---- init: pin this WG's cell-L2 weight K-slice into LDS
  {
    const int nt = wg & 63, role = wg >> 6;
    const float* Wsrc = (role < 2) ? c2Wih : c2Whh;
    const int colOff = (role & 1) * 512;
    for (int rr = 0; rr < 64; rr++) {  // rr = gate*16 + r16
      const int g = rr >> 4, r16 = rr & 15;
      const float* srow = Wsrc + ((size_t)g * H_ + nt * 16 + r16) * 1024 + colOff;
      for (int q = threadIdx.x; q < 512; q += WGS)
        pinW[rr * PIN_STRIDE + q] = f2bf(srow[q]);
    }
  }
  gbar_init(bar);  // full fences ONCE: publish plain-stored weights

  // phase p runs layer-1 step t=p and layer-2 step t=p-1 concurrently
  for (int p = 0; p <= T_; ++p) {
    const int q = p & 1;
    const int q2 = 1 - q;
    const bool doL1 = (p < T_);
    const bool doL2 = (p > 0);
    float* h1q = q ? h1f1 : h1f0;
    float* h1o = q ? h1f0 : h1f1;
    unsigned short* h1sq = q ? h1s1 : h1s0;
    unsigned short* h1so = q ? h1s0 : h1s1;
    float* h2q2 = q2 ? h2f1 : h2f0;
    float* h2o = q ? h2f1 : h2f0;
    unsigned short* h2sq2 = q2 ? h2s1 : h2s0;
    unsigned short* h2so = q ? h2s1 : h2s0;

    for (int s = 0; s < 7; ++s) {
      if (s < 5) {
        const int u2 = doL2 ? 256 : 0;
        const int u1 = doL1 ? ((s == 1 || s == 3) ? 256 : 32) : 0;
        for (int u = wg; u < u2 + u1; u += NWG) {
          if (u < u2) {
            const int lu = u;  // layer 2, step p-1
            switch (s) {
              case 0: mog_unit<1024>(h2sq2, wq2, c2Qb, h1q, H_, x2f, x2s, H_, 6, lu, As, red); break;
              case 1: mog_unit<1024>(x2s, wr2, c2Rb, h2q2, H_, h2q2, h2sq2, H_, 6, lu, As, red); break;
              case 2: mog_unit<1024>(h2sq2, wq2 + 1ull * H_ * H_, c2Qb + H_, x2f, H_, x2f, x2s, H_, 6, lu, As, red); break;
              case 3: mog_unit<1024>(x2s, wr2 + 1ull * H_ * H_, c2Rb + H_, h2q2, H_, h2q2, h2sq2, H_, 6, lu, As, red); break;
              case 4: mog_unit<1024>(h2sq2, wq2 + 2ull * H_ * H_, c2Qb + 2 * H_, x2f, H_, x2f, x2s, H_, 6, lu, As, red); break;
            }
          } else {
            const int lu = u - u2;  // layer 1, step p
            switch (s) {
              case 0: mog_unit<1024>(h1sq, wq1, c1Qb, in_seq + (size_t)p * I_, T_ * I_, x1f, x1s, I_, 3, lu, As, red); break;
              case 1: mog_unit<128>(x1s, wr1, c1Rb, h1q, H_, h1q, h1sq, H_, 6, lu, As, red); break;
              case 2: mog_unit<1024>(h1sq, wq1 + 1ull * I_ * H_, c1Qb + I_, x1f, I_, x1f, x1s, I_, 3, lu, As, red); break;
              case 3: mog_unit<128>(x1s, wr1 + 1ull * H_ * I_, c1Rb + H_, h1q, H_, h1q, h1sq, H_, 6, lu, As, red); break;
              case 4: mog_unit<1024>(h1sq, wq1 + 2ull * I_ * H_, c1Qb + 2 * I_, x1f, I_, x1f, x1s, I_, 3, lu, As, red); break;
            }
          }
        }
      } else if (s == 5) {
        if (doL2) cell2_partial(x2s, h2sq2, pinW, part, wg, As);
        if (doL1) cell1_unit(x1s, h1sq, wih1, whh1, bs1, c1f, h1o, h1so, wg, As, red);
      } else {  // s == 6
        if (doL2) cell2_reduce(part, bs2, c2f, h2o, h2so, wg);
      }
      gbar_fast(bar);
    }
  }

  // ---- final linear: out[b] = dot(h2_final[b,:], linW) + linb (parity 0)
  if (wg == 0) {
    float* rf = (float*)red;
    const int tid = threadIdx.x;
    const int b = tid >> 2, qq = tid & 3;
    const float* row = h2f0 + (size_t)b * H_ + qq * 256;
    const float* w = linW + qq * 256;
    float s = 0.f;
    for (int k = 0; k < 256; k++) s += cloadf(&row[k]) * w[k];
    rf[tid] = s;
    __syncthreads();
    if (tid < B_)
      out[tid] = rf[tid * 4] + rf[tid * 4 + 1] + rf[tid * 4 + 2] + rf[tid * 4 + 3] + linb[0];
  }
}

extern "C" void kernel_launch(void* const* d_in, const int* in_sizes, int n_in,
                              void* d_out, int out_size, void* d_ws, size_t ws_size,
                              hipStream_t stream) {
  const float* in_seq = (const float*)d_in[0];
  const float* c1Q = (const float*)d_in[1];
  const float* c1Qb = (const float*)d_in[2];
  const float* c1R = (const float*)d_in[3];
  const float* c1Rb = (const float*)d_in[4];
  const float* c1Wih = (const float*)d_in[5];
  const float* c1Whh = (const float*)d_in[6];
  const float* c1bih = (const float*)d_in[7];
  const float* c1bhh = (const float*)d_in[8];
  const float* c2Q = (const float*)d_in[9];
  const float* c2Qb = (const float*)d_in[10];
  const float* c2R = (const float*)d_in[11];
  const float* c2Rb = (const float*)d_in[12];
  const float* c2Wih = (const float*)d_in[13];
  const float* c2Whh = (const float*)d_in[14];
  const float* c2bih = (const float*)d_in[15];
  const float* c2bhh = (const float*)d_in[16];
  const float* linW = (const float*)d_in[17];
  const float* linb = (const float*)d_in[18];

  static_assert(DYN_LDS == 133120, "lds layout");
  hipFuncSetAttribute((const void*)moglstm_kernel,
                      hipFuncAttributeMaxDynamicSharedMemorySize, (int)DYN_LDS);
  hipMemsetAsync(d_ws, 0, ZERO_BYTES, stream);
  moglstm_kernel<<<dim3(NWG), dim3(WGS), DYN_LDS, stream>>>(
      in_seq, c1Q, c1Qb, c1R, c1Rb, c1Wih, c1Whh, c1bih, c1bhh,
      c2Q, c2Qb, c2R, c2Rb, c2Wih, c2Whh, c2bih, c2bhh,
      linW, linb, (char*)d_ws, (float*)d_out);
}